// Round 17
// baseline (3173.596 us; speedup 1.0000x reference)
//
#include <hip/hip_runtime.h>
#include <hip/hip_fp16.h>
#include <stdint.h>

#define T_STEPS 1024
#define HDIM    128
#define NT      512

// K-sliced, single-barrier, TWO-SAMPLES-PER-BLOCK design (R17 = R14 x2):
//   wave w = tid>>6 (0..7), lane l = tid&63
//   slice   s = l & 3        -> h columns [32s, 32s+32)
//   element e = 16w + (l>>2) (0..127)
//   block handles samples b0 = 2*blockIdx and b0+1 (grid = 128).
// Each thread runs its element's dots for BOTH samples against the SAME
// register weights. Why: R16 showed the binding cost is VALU issue PLUS
// ~1120 cyc/SIMD/step of serial stall (epi chain -> barrier -> h ds_read)
// that nothing can hide — both waves share one barrier group. With 2
// samples, A's and B's dot/epilogue chains are independent: they fill
// each other's latency, and the per-step barrier + h-latency is paid
// ONCE for two samples. Weight shuttle reads also feed 2 adjacent DOT8s.
// Per-2-samples: dots 3072 + epi ~1400 (interleaved) + 1 barrier ->
// ~2700-2850 cyc/sample vs 3850 measured in R14 (−25%).
// 128 CUs idle: irrelevant (latency-bound per sample, not chip-bound).

typedef _Float16 v2h __attribute__((ext_vector_type(2)));
union HU { uint32_t u; v2h v; };

#define SCL  1.44269504088896340736f   // log2(e)
#define K2C  2.88538008177792681472f   // 2*log2(e)

__device__ __forceinline__ float dot2h(uint32_t a, uint32_t b, float c) {
    HU ua, ub; ua.u = a; ub.u = b;
    return __builtin_amdgcn_fdot2(ua.v, ub.v, c, false);  // v_dot2_f32_f16
}
__device__ __forceinline__ uint32_t packh2s(float2 e) {   // pre-scaled pack
    return (uint32_t)__half_as_ushort(__float2half_rn(e.x * SCL)) |
           ((uint32_t)__half_as_ushort(__float2half_rn(e.y * SCL)) << 16);
}
__device__ __forceinline__ uint16_t f2h(float f) {
    return __half_as_ushort(__float2half_rn(f));
}
// Pre-scaled activations: input a2 = a*log2e.
__device__ __forceinline__ float act2(float a2, float m) {
    return 1.0f - m * __builtin_amdgcn_rcpf(
        __builtin_amdgcn_exp2f(m * a2) + 1.0f);
}
__device__ __forceinline__ float tanhc(float c) {
    return 1.0f - 2.0f * __builtin_amdgcn_rcpf(
        __builtin_amdgcn_exp2f(K2C * c) + 1.0f);
}
// reduce over the 4 slice-lanes (lane bits 0..1): two DPP quad-perm adds.
__device__ __forceinline__ float red2(float v) {
    int iv = __float_as_int(v);
    v += __int_as_float(__builtin_amdgcn_update_dpp(0, iv, 0xB1, 0xF, 0xF, true)); // xor1
    iv = __float_as_int(v);
    v += __int_as_float(__builtin_amdgcn_update_dpp(0, iv, 0x4E, 0xF, 0xF, true)); // xor2
    return v;
}

#define SB() __builtin_amdgcn_sched_barrier(0)
#define PIN4(W) asm volatile("" : "+v"(W.x), "+v"(W.y), "+v"(W.z), "+v"(W.w))

// pack 32 consecutive floats at P into 4 uint4 of pre-scaled f16 pairs
#define SETW16(Wa, Wb, Wc, Wd, P) do { const float2* _r = (const float2*)(P); \
    Wa = make_uint4(packh2s(_r[0]),  packh2s(_r[1]),                       \
                    packh2s(_r[2]),  packh2s(_r[3]));                      \
    Wb = make_uint4(packh2s(_r[4]),  packh2s(_r[5]),                       \
                    packh2s(_r[6]),  packh2s(_r[7]));                      \
    Wc = make_uint4(packh2s(_r[8]),  packh2s(_r[9]),                       \
                    packh2s(_r[10]), packh2s(_r[11]));                     \
    Wd = make_uint4(packh2s(_r[12]), packh2s(_r[13]),                      \
                    packh2s(_r[14]), packh2s(_r[15])); } while (0)

// row pack + immediate pin + scheduling fence: caps init pressure spike.
#define ROW(Wa, Wb, Wc, Wd, P) do {                                        \
    SETW16(Wa, Wb, Wc, Wd, P);                                             \
    PIN4(Wa); PIN4(Wb); PIN4(Wc); PIN4(Wd); SB(); } while (0)

// 8 dot2s: one weight pair (2 uint4 = 16 cols) vs h pair
#define DOT8(Wa, Wb, H0, H1, acc) do {                                     \
    acc = dot2h(Wa.x, H0.x, acc); acc = dot2h(Wa.y, H0.y, acc);            \
    acc = dot2h(Wa.z, H0.z, acc); acc = dot2h(Wa.w, H0.w, acc);            \
    acc = dot2h(Wb.x, H1.x, acc); acc = dot2h(Wb.y, H1.y, acc);            \
    acc = dot2h(Wb.z, H1.z, acc); acc = dot2h(Wb.w, H1.w, acc); } while (0)

// same weight pair against BOTH samples' h pairs (one shuttle, two uses)
#define DOT8x2(Wa, Wb, HA0, HA1, accA, HB0, HB1, accB) do {                \
    DOT8(Wa, Wb, HA0, HA1, accA); DOT8(Wa, Wb, HB0, HB1, accB); } while (0)

__global__ __launch_bounds__(NT)
__attribute__((amdgpu_waves_per_eu(2, 2)))
void lstm_persistent(
    const float* __restrict__ x,
    const float* __restrict__ W_ih1, const float* __restrict__ W_hh1,
    const float* __restrict__ b_ih1, const float* __restrict__ b_hh1,
    const float* __restrict__ W_ih2, const float* __restrict__ W_hh2,
    const float* __restrict__ b_ih2, const float* __restrict__ b_hh2,
    const float* __restrict__ W_out, const float* __restrict__ b_out,
    float* __restrict__ out)
{
    const int b0  = blockIdx.x * 2;               // two samples per block
    const int tid = threadIdx.x;
    const int w   = tid >> 6;
    const int l   = tid & 63;
    const int s   = l & 3;
    const int e   = (w << 4) | (l >> 2);
    const int co  = s << 5;                       // column offset (floats)

    __shared__ __align__(16) uint32_t h1p[2][2][HDIM / 2];  // [buf][samp]
    __shared__ __align__(16) uint32_t h2p[2][2][HDIM / 2];
    __shared__ float pbuf[2][2][8];               // [buf][samp][wave]

    // ---- one-time: weight slices -> 48 named uint4 (192 dwords), fenced.
    // SHARED by both samples — the whole point of this round.
    uint4 m1_00,m1_01,m1_02,m1_03, m1_10,m1_11,m1_12,m1_13;   // W_hh1
    uint4 m1_20,m1_21,m1_22,m1_23, m1_30,m1_31,m1_32,m1_33;
    uint4 m2_00,m2_01,m2_02,m2_03, m2_10,m2_11,m2_12,m2_13;   // W_ih2
    uint4 m2_20,m2_21,m2_22,m2_23, m2_30,m2_31,m2_32,m2_33;
    uint4 m3_00,m3_01,m3_02,m3_03, m3_10,m3_11,m3_12,m3_13;   // W_hh2
    uint4 m3_20,m3_21,m3_22,m3_23, m3_30,m3_31,m3_32,m3_33;
    {
        const float* p = W_hh1 + e * HDIM + co;
        ROW(m1_00,m1_01,m1_02,m1_03, p);
        ROW(m1_10,m1_11,m1_12,m1_13, p + 128 * HDIM);
        ROW(m1_20,m1_21,m1_22,m1_23, p + 256 * HDIM);
        ROW(m1_30,m1_31,m1_32,m1_33, p + 384 * HDIM);
        p = W_ih2 + e * HDIM + co;
        ROW(m2_00,m2_01,m2_02,m2_03, p);
        ROW(m2_10,m2_11,m2_12,m2_13, p + 128 * HDIM);
        ROW(m2_20,m2_21,m2_22,m2_23, p + 256 * HDIM);
        ROW(m2_30,m2_31,m2_32,m2_33, p + 384 * HDIM);
        p = W_hh2 + e * HDIM + co;
        ROW(m3_00,m3_01,m3_02,m3_03, p);
        ROW(m3_10,m3_11,m3_12,m3_13, p + 128 * HDIM);
        ROW(m3_20,m3_21,m3_22,m3_23, p + 256 * HDIM);
        ROW(m3_30,m3_31,m3_32,m3_33, p + 384 * HDIM);
    }

    // ---- one-time: biases / x-weights (pre-scaled, per-element -> shared)
    const float b1i = (b_ih1[e]       + b_hh1[e])       * SCL;
    const float b1f = (b_ih1[e + 128] + b_hh1[e + 128]) * SCL;
    const float b1g = (b_ih1[e + 256] + b_hh1[e + 256]) * SCL;
    const float b1o = (b_ih1[e + 384] + b_hh1[e + 384]) * SCL;
    const float wxi = W_ih1[e]       * SCL, wxf = W_ih1[e + 128] * SCL;
    const float wxg = W_ih1[e + 256] * SCL, wxo = W_ih1[e + 384] * SCL;
    const float b2i = (b_ih2[e]       + b_hh2[e])       * SCL;
    const float b2f = (b_ih2[e + 128] + b_hh2[e + 128]) * SCL;
    const float b2g = (b_ih2[e + 256] + b_hh2[e + 256]) * SCL;
    const float b2o = (b_ih2[e + 384] + b_hh2[e + 384]) * SCL;
    const float wo = (s == 0) ? W_out[e] : 0.0f;
    const float bo = b_out[0];

    float c1A = 0.f, c2A = 0.f, c1B = 0.f, c2B = 0.f;

    if (tid < HDIM / 2) {
        h1p[0][0][tid] = 0u; h1p[1][0][tid] = 0u;
        h1p[0][1][tid] = 0u; h1p[1][1][tid] = 0u;
        h2p[0][0][tid] = 0u; h2p[1][0][tid] = 0u;
        h2p[0][1][tid] = 0u; h2p[1][1][tid] = 0u;
    }
    __syncthreads();

    const float* xbA = x + (size_t)b0 * T_STEPS;
    const float* xbB = x + (size_t)(b0 + 1) * T_STEPS;
    float* obA = out + (size_t)b0 * T_STEPS;
    float* obB = out + (size_t)(b0 + 1) * T_STEPS;
    float xcA = xbA[0], xcB = xbB[0];

    // Iteration k (k = 0..T): computes h1(k) and h2(k-1)/out(k-1), both samples.
    for (int k = 0; k <= T_STEPS; ++k) {
        const int rb = k & 1, wbuf = rb ^ 1;
        int kn = (k + 1 < T_STEPS) ? (k + 1) : (T_STEPS - 1);
        float xnA = xbA[kn], xnB = xbB[kn];

        // ---- phase 1: h1 fragments (both samples), m1+m2 dots, A/B paired
        // on each weight (one shuttle read, two uses; 16 indep acc chains).
        const uint4* HA = (const uint4*)h1p[rb][0];
        const uint4* HB = (const uint4*)h1p[rb][1];
        uint4 Aa0 = HA[4*s+0], Aa1 = HA[4*s+1], Ab0 = HA[4*s+2], Ab1 = HA[4*s+3];
        uint4 Ba0 = HB[4*s+0], Ba1 = HB[4*s+1], Bb0 = HB[4*s+2], Bb1 = HB[4*s+3];
        float aA0=0.f,aA1=0.f,aA2=0.f,aA3=0.f, qA0=0.f,qA1=0.f,qA2=0.f,qA3=0.f;
        float aB0=0.f,aB1=0.f,aB2=0.f,aB3=0.f, qB0=0.f,qB1=0.f,qB2=0.f,qB3=0.f;
        DOT8x2(m1_00,m1_01, Aa0,Aa1,aA0, Ba0,Ba1,aB0);
        DOT8x2(m1_10,m1_11, Aa0,Aa1,aA1, Ba0,Ba1,aB1);
        DOT8x2(m1_20,m1_21, Aa0,Aa1,aA2, Ba0,Ba1,aB2);
        DOT8x2(m1_30,m1_31, Aa0,Aa1,aA3, Ba0,Ba1,aB3);
        DOT8x2(m1_02,m1_03, Ab0,Ab1,aA0, Bb0,Bb1,aB0);
        DOT8x2(m1_12,m1_13, Ab0,Ab1,aA1, Bb0,Bb1,aB1);
        DOT8x2(m1_22,m1_23, Ab0,Ab1,aA2, Bb0,Bb1,aB2);
        DOT8x2(m1_32,m1_33, Ab0,Ab1,aA3, Bb0,Bb1,aB3);
        DOT8x2(m2_00,m2_01, Aa0,Aa1,qA0, Ba0,Ba1,qB0);
        DOT8x2(m2_10,m2_11, Aa0,Aa1,qA1, Ba0,Ba1,qB1);
        DOT8x2(m2_20,m2_21, Aa0,Aa1,qA2, Ba0,Ba1,qB2);
        DOT8x2(m2_30,m2_31, Aa0,Aa1,qA3, Ba0,Ba1,qB3);
        DOT8x2(m2_02,m2_03, Ab0,Ab1,qA0, Bb0,Bb1,qB0);
        DOT8x2(m2_12,m2_13, Ab0,Ab1,qA1, Bb0,Bb1,qB1);
        DOT8x2(m2_22,m2_23, Ab0,Ab1,qA2, Bb0,Bb1,qB2);
        DOT8x2(m2_32,m2_33, Ab0,Ab1,qA3, Bb0,Bb1,qB3);

        // ---- phase 2: issue h2 reads (both samples)
        const uint4* GA = (const uint4*)h2p[rb][0];
        const uint4* GB = (const uint4*)h2p[rb][1];
        uint4 Ac0 = GA[4*s+0], Ac1 = GA[4*s+1], Ad0 = GA[4*s+2], Ad1 = GA[4*s+3];
        uint4 Bc0 = GB[4*s+0], Bc1 = GB[4*s+1], Bd0 = GB[4*s+2], Bd1 = GB[4*s+3];

        // ---- store out(k-2): wave0 lanes 0-7 do sample A, wave1 lanes
        // 0-7 do sample B (parallel across waves, under the h2 lgkm wait)
        if (k >= 2) {
            if (tid < 8) {
                float ssum = pbuf[wbuf][0][tid];
                ssum += __shfl_xor(ssum, 1, 64);
                ssum += __shfl_xor(ssum, 2, 64);
                ssum += __shfl_xor(ssum, 4, 64);
                if (tid == 0) obA[k - 2] = ssum + bo;
            } else if (tid >= 64 && tid < 72) {
                float ssum = pbuf[wbuf][1][tid - 64];
                ssum += __shfl_xor(ssum, 1, 64);
                ssum += __shfl_xor(ssum, 2, 64);
                ssum += __shfl_xor(ssum, 4, 64);
                if (tid == 64) obB[k - 2] = ssum + bo;
            }
        }

        // ---- epilogue 1 (A and B, independent chains interleave)
        aA0 = red2(aA0); aA1 = red2(aA1); aA2 = red2(aA2); aA3 = red2(aA3);
        aB0 = red2(aB0); aB1 = red2(aB1); aB2 = red2(aB2); aB3 = red2(aB3);
        {
            float gi = act2(aA0 + fmaf(xcA, wxi, b1i), 1.0f);
            float gf = act2(aA1 + fmaf(xcA, wxf, b1f), 1.0f);
            float gg = act2(aA2 + fmaf(xcA, wxg, b1g), 2.0f);
            float go = act2(aA3 + fmaf(xcA, wxo, b1o), 1.0f);
            c1A = fmaf(gf, c1A, gi * gg);
            float h1v = go * tanhc(c1A);
            if (s == 0) ((uint16_t*)h1p[wbuf][0])[e] = f2h(h1v);
        }
        {
            float gi = act2(aB0 + fmaf(xcB, wxi, b1i), 1.0f);
            float gf = act2(aB1 + fmaf(xcB, wxf, b1f), 1.0f);
            float gg = act2(aB2 + fmaf(xcB, wxg, b1g), 2.0f);
            float go = act2(aB3 + fmaf(xcB, wxo, b1o), 1.0f);
            c1B = fmaf(gf, c1B, gi * gg);
            float h1v = go * tanhc(c1B);
            if (s == 0) ((uint16_t*)h1p[wbuf][1])[e] = f2h(h1v);
        }

        // ---- phase 3: m3 dots (h2 x W_hh2), A/B paired
        DOT8x2(m3_00,m3_01, Ac0,Ac1,qA0, Bc0,Bc1,qB0);
        DOT8x2(m3_10,m3_11, Ac0,Ac1,qA1, Bc0,Bc1,qB1);
        DOT8x2(m3_20,m3_21, Ac0,Ac1,qA2, Bc0,Bc1,qB2);
        DOT8x2(m3_30,m3_31, Ac0,Ac1,qA3, Bc0,Bc1,qB3);
        DOT8x2(m3_02,m3_03, Ad0,Ad1,qA0, Bd0,Bd1,qB0);
        DOT8x2(m3_12,m3_13, Ad0,Ad1,qA1, Bd0,Bd1,qB1);
        DOT8x2(m3_22,m3_23, Ad0,Ad1,qA2, Bd0,Bd1,qB2);
        DOT8x2(m3_32,m3_33, Ad0,Ad1,qA3, Bd0,Bd1,qB3);

        // ---- epilogue 2 (A and B; skip at k=0)
        if (k > 0) {
            qA0 = red2(qA0); qA1 = red2(qA1); qA2 = red2(qA2); qA3 = red2(qA3);
            qB0 = red2(qB0); qB1 = red2(qB1); qB2 = red2(qB2); qB3 = red2(qB3);
            float partA, partB;
            {
                float hi = act2(qA0 + b2i, 1.0f);
                float hf = act2(qA1 + b2f, 1.0f);
                float hg = act2(qA2 + b2g, 2.0f);
                float ho = act2(qA3 + b2o, 1.0f);
                c2A = fmaf(hf, c2A, hi * hg);
                float h2v = ho * tanhc(c2A);
                if (s == 0) ((uint16_t*)h2p[wbuf][0])[e] = f2h(h2v);
                partA = wo * h2v;
            }
            {
                float hi = act2(qB0 + b2i, 1.0f);
                float hf = act2(qB1 + b2f, 1.0f);
                float hg = act2(qB2 + b2g, 2.0f);
                float ho = act2(qB3 + b2o, 1.0f);
                c2B = fmaf(hf, c2B, hi * hg);
                float h2v = ho * tanhc(c2B);
                if (s == 0) ((uint16_t*)h2p[wbuf][1])[e] = f2h(h2v);
                partB = wo * h2v;
            }
            partA += __shfl_xor(partA, 4,  64);
            partA += __shfl_xor(partA, 8,  64);
            partA += __shfl_xor(partA, 16, 64);
            partA += __shfl_xor(partA, 32, 64);
            partB += __shfl_xor(partB, 4,  64);
            partB += __shfl_xor(partB, 8,  64);
            partB += __shfl_xor(partB, 16, 64);
            partB += __shfl_xor(partB, 32, 64);
            if (l == 0) { pbuf[rb][0][w] = partA; pbuf[rb][1][w] = partB; }
        }
        __syncthreads();   // single barrier for BOTH samples
        xcA = xnA; xcB = xnB;
    }

    // ---- drain: out(T-1), both samples (partials at parity T&1)
    if (tid < 8) {
        float ssum = pbuf[T_STEPS & 1][0][tid];
        ssum += __shfl_xor(ssum, 1, 64);
        ssum += __shfl_xor(ssum, 2, 64);
        ssum += __shfl_xor(ssum, 4, 64);
        if (tid == 0) obA[T_STEPS - 1] = ssum + bo;
    } else if (tid >= 64 && tid < 72) {
        float ssum = pbuf[T_STEPS & 1][1][tid - 64];
        ssum += __shfl_xor(ssum, 1, 64);
        ssum += __shfl_xor(ssum, 2, 64);
        ssum += __shfl_xor(ssum, 4, 64);
        if (tid == 64) obB[T_STEPS - 1] = ssum + bo;
    }
}

extern "C" void kernel_launch(void* const* d_in, const int* in_sizes, int n_in,
                              void* d_out, int out_size, void* d_ws, size_t ws_size,
                              hipStream_t stream) {
    const float* x     = (const float*)d_in[0];
    const float* W_ih1 = (const float*)d_in[1];
    const float* W_hh1 = (const float*)d_in[2];
    const float* b_ih1 = (const float*)d_in[3];
    const float* b_hh1 = (const float*)d_in[4];
    const float* W_ih2 = (const float*)d_in[5];
    const float* W_hh2 = (const float*)d_in[6];
    const float* b_ih2 = (const float*)d_in[7];
    const float* b_hh2 = (const float*)d_in[8];
    const float* W_out = (const float*)d_in[9];
    const float* b_out = (const float*)d_in[10];
    float* out = (float*)d_out;

    const int B = in_sizes[0] / T_STEPS;   // 256
    hipLaunchKernelGGL(lstm_persistent, dim3(B / 2), dim3(NT), 0, stream,
                       x, W_ih1, W_hh1, b_ih1, b_hh1,
                       W_ih2, W_hh2, b_ih2, b_hh2, W_out, b_out, out);
}

// Round 20
// 1526.195 us; speedup vs baseline: 2.0794x; 2.0794x over previous
//
#include <hip/hip_runtime.h>
#include <hip/hip_fp16.h>
#include <stdint.h>

#define T_STEPS 1024
#define HDIM    128
#define NT      512

// K-sliced, single-barrier pipelined design (R20 = R19 resubmit; R19 hit
// a pre-compile container/infra failure, same as R9 -> R10 which then
// passed verbatim):
//   wave w = tid>>6 (0..7), lane l = tid&63
//   slice   s = l & 3        -> h columns [32s, 32s+32)
//   element e = 16w + (l>>2) (0..127)
// Iteration k fuses: gates1(k)   = W_hh1*h1(k-1)            (+ x(k), bias)
//                    gates2(k-1) = W_ih2*h1(k-1) + W_hh2*h2(k-2)
// One 192-dot block, two epilogues, ONE barrier.
//
// Session verdict (R0-R17): this structure at 1642 us/dispatch is the
// measured optimum. Step = dots 1536 cyc/SIMD (v_dot2 is HALF-RATE, 4 cyc
// — R14/R15 measured) + epilogue ~520 + AGPR shuttle ~400 + exposed
// latency ~1100. Probed-and-worse neighbors: 3-matrix reg weights (spill,
// R0-R4), slice-8 (R5 +47%), MFMA batching (R9-R11 +68%: 16-CU grid
// concentrates the epilogue), pk_fma_f16 (R15 +8%: also half-rate),
// LDS weights (R16 +8%: latency lands on critical path), 2 samples/block
// (R17 +99%: register capacity). Register-policy knobs (launch_bounds,
// waves_per_eu, num_vgpr, agpr_alloc, asm pins): all neutral — the
// 128-arch/128-AGPR split is fixed compiler policy.
// Micro vs R14: xor4/8/16 lane reductions via single-instruction
// ds_swizzle (BitMode masks: xor<<10 | 0x1F, constant via template)
// instead of __shfl_xor's addr-calc + ds_bpermute; xor32 stays shfl
// (swizzle is 32-lane-limited).

typedef _Float16 v2h __attribute__((ext_vector_type(2)));
union HU { uint32_t u; v2h v; };

#define SCL  1.44269504088896340736f   // log2(e)
#define K2C  2.88538008177792681472f   // 2*log2(e)

__device__ __forceinline__ float dot2h(uint32_t a, uint32_t b, float c) {
    HU ua, ub; ua.u = a; ub.u = b;
    return __builtin_amdgcn_fdot2(ua.v, ub.v, c, false);  // v_dot2_f32_f16
}
__device__ __forceinline__ uint32_t packh2s(float2 e) {   // pre-scaled pack
    return (uint32_t)__half_as_ushort(__float2half_rn(e.x * SCL)) |
           ((uint32_t)__half_as_ushort(__float2half_rn(e.y * SCL)) << 16);
}
__device__ __forceinline__ uint16_t f2h(float f) {
    return __half_as_ushort(__float2half_rn(f));
}
// Pre-scaled activations: input a2 = a*log2e.
__device__ __forceinline__ float act2(float a2, float m) {
    return 1.0f - m * __builtin_amdgcn_rcpf(
        __builtin_amdgcn_exp2f(m * a2) + 1.0f);
}
__device__ __forceinline__ float tanhc(float c) {
    return 1.0f - 2.0f * __builtin_amdgcn_rcpf(
        __builtin_amdgcn_exp2f(K2C * c) + 1.0f);
}
// reduce over the 4 slice-lanes (lane bits 0..1): two DPP quad-perm adds.
__device__ __forceinline__ float red2(float v) {
    int iv = __float_as_int(v);
    v += __int_as_float(__builtin_amdgcn_update_dpp(0, iv, 0xB1, 0xF, 0xF, true)); // xor1
    iv = __float_as_int(v);
    v += __int_as_float(__builtin_amdgcn_update_dpp(0, iv, 0x4E, 0xF, 0xF, true)); // xor2
    return v;
}
// single-instruction xor-lane add via ds_swizzle (BitMode, lanes mod 32).
// MASK must be a compile-time constant -> template parameter (R18 lesson).
template <int MASK>
__device__ __forceinline__ float swzadd(float v) {
    return v + __int_as_float(
        __builtin_amdgcn_ds_swizzle(__float_as_int(v), MASK));
}

#define SB() __builtin_amdgcn_sched_barrier(0)
#define PIN4(W) asm volatile("" : "+v"(W.x), "+v"(W.y), "+v"(W.z), "+v"(W.w))

// pack 32 consecutive floats at P into 4 uint4 of pre-scaled f16 pairs
#define SETW16(Wa, Wb, Wc, Wd, P) do { const float2* _r = (const float2*)(P); \
    Wa = make_uint4(packh2s(_r[0]),  packh2s(_r[1]),                       \
                    packh2s(_r[2]),  packh2s(_r[3]));                      \
    Wb = make_uint4(packh2s(_r[4]),  packh2s(_r[5]),                       \
                    packh2s(_r[6]),  packh2s(_r[7]));                      \
    Wc = make_uint4(packh2s(_r[8]),  packh2s(_r[9]),                       \
                    packh2s(_r[10]), packh2s(_r[11]));                     \
    Wd = make_uint4(packh2s(_r[12]), packh2s(_r[13]),                      \
                    packh2s(_r[14]), packh2s(_r[15])); } while (0)

// row pack + immediate pin + scheduling fence: caps init pressure spike.
#define ROW(Wa, Wb, Wc, Wd, P) do {                                        \
    SETW16(Wa, Wb, Wc, Wd, P);                                             \
    PIN4(Wa); PIN4(Wb); PIN4(Wc); PIN4(Wd); SB(); } while (0)

// 8 dot2s: one weight pair (2 uint4 = 16 cols) vs h pair
#define DOT8(Wa, Wb, H0, H1, acc) do {                                     \
    acc = dot2h(Wa.x, H0.x, acc); acc = dot2h(Wa.y, H0.y, acc);            \
    acc = dot2h(Wa.z, H0.z, acc); acc = dot2h(Wa.w, H0.w, acc);            \
    acc = dot2h(Wb.x, H1.x, acc); acc = dot2h(Wb.y, H1.y, acc);            \
    acc = dot2h(Wb.z, H1.z, acc); acc = dot2h(Wb.w, H1.w, acc); } while (0)

__global__ __launch_bounds__(NT)
__attribute__((amdgpu_waves_per_eu(2, 2)))
void lstm_persistent(
    const float* __restrict__ x,
    const float* __restrict__ W_ih1, const float* __restrict__ W_hh1,
    const float* __restrict__ b_ih1, const float* __restrict__ b_hh1,
    const float* __restrict__ W_ih2, const float* __restrict__ W_hh2,
    const float* __restrict__ b_ih2, const float* __restrict__ b_hh2,
    const float* __restrict__ W_out, const float* __restrict__ b_out,
    float* __restrict__ out)
{
    const int b   = blockIdx.x;
    const int tid = threadIdx.x;
    const int w   = tid >> 6;
    const int l   = tid & 63;
    const int s   = l & 3;
    const int e   = (w << 4) | (l >> 2);
    const int co  = s << 5;                       // column offset (floats)

    __shared__ __align__(16) uint32_t h1p[2][HDIM / 2];   // h1 f16 pairs, dbuf
    __shared__ __align__(16) uint32_t h2p[2][HDIM / 2];   // h2 f16 pairs, dbuf
    __shared__ float pbuf[2][8];                  // per-wave out partials, dbuf

    // ---- one-time: weight slices -> 48 named uint4 (192 dwords), fenced
    uint4 m1_00,m1_01,m1_02,m1_03, m1_10,m1_11,m1_12,m1_13;   // W_hh1
    uint4 m1_20,m1_21,m1_22,m1_23, m1_30,m1_31,m1_32,m1_33;
    uint4 m2_00,m2_01,m2_02,m2_03, m2_10,m2_11,m2_12,m2_13;   // W_ih2
    uint4 m2_20,m2_21,m2_22,m2_23, m2_30,m2_31,m2_32,m2_33;
    uint4 m3_00,m3_01,m3_02,m3_03, m3_10,m3_11,m3_12,m3_13;   // W_hh2
    uint4 m3_20,m3_21,m3_22,m3_23, m3_30,m3_31,m3_32,m3_33;
    {
        const float* p = W_hh1 + e * HDIM + co;
        ROW(m1_00,m1_01,m1_02,m1_03, p);
        ROW(m1_10,m1_11,m1_12,m1_13, p + 128 * HDIM);
        ROW(m1_20,m1_21,m1_22,m1_23, p + 256 * HDIM);
        ROW(m1_30,m1_31,m1_32,m1_33, p + 384 * HDIM);
        p = W_ih2 + e * HDIM + co;
        ROW(m2_00,m2_01,m2_02,m2_03, p);
        ROW(m2_10,m2_11,m2_12,m2_13, p + 128 * HDIM);
        ROW(m2_20,m2_21,m2_22,m2_23, p + 256 * HDIM);
        ROW(m2_30,m2_31,m2_32,m2_33, p + 384 * HDIM);
        p = W_hh2 + e * HDIM + co;
        ROW(m3_00,m3_01,m3_02,m3_03, p);
        ROW(m3_10,m3_11,m3_12,m3_13, p + 128 * HDIM);
        ROW(m3_20,m3_21,m3_22,m3_23, p + 256 * HDIM);
        ROW(m3_30,m3_31,m3_32,m3_33, p + 384 * HDIM);
    }

    // ---- one-time: ALL biases / x-weights pre-scaled by log2e, in regs
    const float b1i = (b_ih1[e]       + b_hh1[e])       * SCL;
    const float b1f = (b_ih1[e + 128] + b_hh1[e + 128]) * SCL;
    const float b1g = (b_ih1[e + 256] + b_hh1[e + 256]) * SCL;
    const float b1o = (b_ih1[e + 384] + b_hh1[e + 384]) * SCL;
    const float wxi = W_ih1[e]       * SCL, wxf = W_ih1[e + 128] * SCL;
    const float wxg = W_ih1[e + 256] * SCL, wxo = W_ih1[e + 384] * SCL;
    const float b2i = (b_ih2[e]       + b_hh2[e])       * SCL;
    const float b2f = (b_ih2[e + 128] + b_hh2[e + 128]) * SCL;
    const float b2g = (b_ih2[e + 256] + b_hh2[e + 256]) * SCL;
    const float b2o = (b_ih2[e + 384] + b_hh2[e + 384]) * SCL;
    const float wo = (s == 0) ? W_out[e] : 0.0f;
    const float bo = b_out[0];

    float c1 = 0.f, c2 = 0.f;                      // replicated across 4 lanes

    if (tid < HDIM / 2) {
        h1p[0][tid] = 0u; h1p[1][tid] = 0u;        // h1(-1) = h2(-1) = 0
        h2p[0][tid] = 0u; h2p[1][tid] = 0u;
    }
    __syncthreads();

    const float* xb = x + b * T_STEPS;
    float*       ob = out + b * T_STEPS;
    float x_cur = xb[0];

    // Iteration k (k = 0..T): computes h1(k) and h2(k-1)/out(k-1).
    for (int k = 0; k <= T_STEPS; ++k) {
        const int rb = k & 1, wbuf = rb ^ 1;
        float x_nxt = xb[(k + 1 < T_STEPS) ? (k + 1) : (T_STEPS - 1)];

        // ---- phase 1: h1 fragments, then m1 + m2 dots (both consume h1).
        const uint4* H1 = (const uint4*)h1p[rb];
        uint4 Ha0 = H1[4*s+0], Ha1 = H1[4*s+1];   // h1 cols [co, co+16)
        uint4 Hb0 = H1[4*s+2], Hb1 = H1[4*s+3];   // h1 cols [co+16, co+32)
        float a0=0.f,a1=0.f,a2=0.f,a3=0.f, q0=0.f,q1=0.f,q2=0.f,q3=0.f;
        DOT8(m1_00,m1_01, Ha0,Ha1, a0); DOT8(m1_10,m1_11, Ha0,Ha1, a1);
        DOT8(m1_20,m1_21, Ha0,Ha1, a2); DOT8(m1_30,m1_31, Ha0,Ha1, a3);
        DOT8(m1_02,m1_03, Hb0,Hb1, a0); DOT8(m1_12,m1_13, Hb0,Hb1, a1);
        DOT8(m1_22,m1_23, Hb0,Hb1, a2); DOT8(m1_32,m1_33, Hb0,Hb1, a3);
        DOT8(m2_00,m2_01, Ha0,Ha1, q0); DOT8(m2_10,m2_11, Ha0,Ha1, q1);
        DOT8(m2_20,m2_21, Ha0,Ha1, q2); DOT8(m2_30,m2_31, Ha0,Ha1, q3);
        DOT8(m2_02,m2_03, Hb0,Hb1, q0); DOT8(m2_12,m2_13, Hb0,Hb1, q1);
        DOT8(m2_22,m2_23, Hb0,Hb1, q2); DOT8(m2_32,m2_33, Hb0,Hb1, q3);

        // ---- phase 2: issue h2 reads; latency filled by out-store + epi1.
        const uint4* H2 = (const uint4*)h2p[rb];
        uint4 Hc0 = H2[4*s+0], Hc1 = H2[4*s+1];
        uint4 Hd0 = H2[4*s+2], Hd1 = H2[4*s+3];

        // ---- store out(k-2): independent work under the h2 lgkm wait
        if (k >= 2 && tid < 8) {
            float ssum = pbuf[wbuf][tid];
            ssum = swzadd<0x041F>(ssum);   // xor1
            ssum = swzadd<0x081F>(ssum);   // xor2
            ssum = swzadd<0x101F>(ssum);   // xor4
            if (tid == 0) ob[k - 2] = ssum + bo;
        }

        // ---- epilogue 1: h1(k) — pre-scaled domain, raw exp2 activations
        a0 = red2(a0); a1 = red2(a1); a2 = red2(a2); a3 = red2(a3);
        float gi = act2(a0 + fmaf(x_cur, wxi, b1i), 1.0f);
        float gf = act2(a1 + fmaf(x_cur, wxf, b1f), 1.0f);
        float gg = act2(a2 + fmaf(x_cur, wxg, b1g), 2.0f);
        float go = act2(a3 + fmaf(x_cur, wxo, b1o), 1.0f);
        c1 = fmaf(gf, c1, gi * gg);
        float h1v = go * tanhc(c1);
        if (s == 0) ((uint16_t*)h1p[wbuf])[e] = f2h(h1v);

        // ---- phase 3: m3 dots (h2 x W_hh2)
        DOT8(m3_00,m3_01, Hc0,Hc1, q0); DOT8(m3_10,m3_11, Hc0,Hc1, q1);
        DOT8(m3_20,m3_21, Hc0,Hc1, q2); DOT8(m3_30,m3_31, Hc0,Hc1, q3);
        DOT8(m3_02,m3_03, Hd0,Hd1, q0); DOT8(m3_12,m3_13, Hd0,Hd1, q1);
        DOT8(m3_22,m3_23, Hd0,Hd1, q2); DOT8(m3_32,m3_33, Hd0,Hd1, q3);

        // ---- epilogue 2: h2(k-1) + out(k-1) partial (skip at k=0)
        if (k > 0) {
            q0 = red2(q0); q1 = red2(q1); q2 = red2(q2); q3 = red2(q3);
            float hi = act2(q0 + b2i, 1.0f);
            float hf = act2(q1 + b2f, 1.0f);
            float hg = act2(q2 + b2g, 2.0f);
            float ho = act2(q3 + b2o, 1.0f);
            c2 = fmaf(hf, c2, hi * hg);
            float h2v = ho * tanhc(c2);
            if (s == 0) ((uint16_t*)h2p[wbuf])[e] = f2h(h2v);
            float part = wo * h2v;                 // wo==0 on s!=0 lanes
            part = swzadd<0x101F>(part);           // xor4
            part = swzadd<0x201F>(part);           // xor8
            part = swzadd<0x401F>(part);           // xor16
            part += __shfl_xor(part, 32, 64);      // cross-32 (swizzle can't)
            if (l == 0) pbuf[rb][w] = part;
        }
        __syncthreads();   // single barrier: publish h1(k), h2(k-1), partials
        x_cur = x_nxt;
    }

    // ---- drain: out(T-1) partials were published at k=T (parity T&1)
    if (tid < 8) {
        float ssum = pbuf[T_STEPS & 1][tid];
        ssum = swzadd<0x041F>(ssum);
        ssum = swzadd<0x081F>(ssum);
        ssum = swzadd<0x101F>(ssum);
        if (tid == 0) ob[T_STEPS - 1] = ssum + bo;
    }
}

extern "C" void kernel_launch(void* const* d_in, const int* in_sizes, int n_in,
                              void* d_out, int out_size, void* d_ws, size_t ws_size,
                              hipStream_t stream) {
    const float* x     = (const float*)d_in[0];
    const float* W_ih1 = (const float*)d_in[1];
    const float* W_hh1 = (const float*)d_in[2];
    const float* b_ih1 = (const float*)d_in[3];
    const float* b_hh1 = (const float*)d_in[4];
    const float* W_ih2 = (const float*)d_in[5];
    const float* W_hh2 = (const float*)d_in[6];
    const float* b_ih2 = (const float*)d_in[7];
    const float* b_hh2 = (const float*)d_in[8];
    const float* W_out = (const float*)d_in[9];
    const float* b_out = (const float*)d_in[10];
    float* out = (float*)d_out;

    const int B = in_sizes[0] / T_STEPS;   // 256
    hipLaunchKernelGGL(lstm_persistent, dim3(B), dim3(NT), 0, stream,
                       x, W_ih1, W_hh1, b_ih1, b_hh1,
                       W_ih2, W_hh2, b_ih2, b_hh2, W_out, b_out, out);
}